// Round 2
// baseline (110.006 us; speedup 1.0000x reference)
//
#include <hip/hip_runtime.h>

typedef __attribute__((ext_vector_type(4))) float  f32x4;
typedef __attribute__((ext_vector_type(8))) __bf16 bf16x8;
typedef __attribute__((ext_vector_type(4))) __bf16 bf16x4;

#define MFMA16(a, b, c) __builtin_amdgcn_mfma_f32_16x16x32_bf16((a), (b), (c), 0, 0, 0)

// One block per (b,h): bs=2048, h=8, dh=32, qsl=sl=64.
// LDS 14.8 KB -> 8 blocks/CU; __launch_bounds__(256,8) -> 32 waves/CU.
__global__ __launch_bounds__(256, 8)
void mha_fused(const float* __restrict__ qg, const float* __restrict__ kg,
               const float* __restrict__ vg, const unsigned char* __restrict__ maskg,
               const float* __restrict__ gammag, const float* __restrict__ biasg,
               float* __restrict__ outg)
{
    // XCD-bijective remap: keep the 8 h-blocks of one b on the same XCD L2
    // (mask is the only cross-block-reused input). gridDim.x % 8 == 0 here.
    const int bid = blockIdx.x;
    const int chunk = gridDim.x >> 3;
    const int bh = (bid & 7) * chunk + (bid >> 3);
    const int b  = bh >> 3;
    const int h  = bh & 7;
    const int t  = threadIdx.x;

    // K^T split-bf16 [j][d], stride 40 bf16 = 80 B; 16B slots XOR-swizzled.
    __shared__ __bf16 sKh[64][40];
    __shared__ __bf16 sKl[64][40];
    __shared__ __bf16 sV [32][72];   // V bf16 [d][j], stride 144 B

    const float* qb = qg + (size_t)bh * 2048;
    const float* kb = kg + (size_t)bh * 2048;
    const float* vb = vg + (size_t)bh * 2048;
    const unsigned char* mb = maskg + (size_t)b * 4096;  // mask broadcast over h
    float* ob = outg + (size_t)bh * 2048;

    const int w  = t >> 6;         // wave id: owns query cols i = w*16..w*16+15
    const int li = t & 15;
    const int hi = (t >> 4) & 3;
    const int i  = w * 16 + li;

    // ---- early: Q fragment direct from global (no cross-wave reuse) ----
    float qv[8];
    #pragma unroll
    for (int e = 0; e < 8; ++e) qv[e] = qb[(hi * 8 + e) * 64 + i];
    // ---- early: mask words (read-once, no staging) ----
    unsigned int mw[4];
    #pragma unroll
    for (int jt = 0; jt < 4; ++jt)
        mw[jt] = *(const unsigned int*)&mb[i * 64 + jt * 16 + hi * 4];

    // ---- stage K^T split-bf16, one 16B slot per thread, XOR slot swizzle ----
    {
        const int j = t & 63, sel = t >> 6;
        float a[8];
        #pragma unroll
        for (int e = 0; e < 8; ++e) a[e] = kb[(sel * 8 + e) * 64 + j];
        bf16x8 h8, l8;
        #pragma unroll
        for (int e = 0; e < 8; ++e) {
            __bf16 hh = (__bf16)a[e];
            h8[e] = hh;
            l8[e] = (__bf16)(a[e] - (float)hh);
        }
        const int slot = sel ^ ((j >> 3) & 3);
        *(bf16x8*)&sKh[j][slot * 8] = h8;
        *(bf16x8*)&sKl[j][slot * 8] = l8;
    }
    // ---- stage V as bf16, natural [d][j] ----
    {
        const int d = t >> 3, j0 = (t & 7) * 8;
        f32x4 x0 = *(const f32x4*)&vb[d * 64 + j0];
        f32x4 x1 = *(const f32x4*)&vb[d * 64 + j0 + 4];
        bf16x8 vv = {(__bf16)x0[0], (__bf16)x0[1], (__bf16)x0[2], (__bf16)x0[3],
                     (__bf16)x1[0], (__bf16)x1[1], (__bf16)x1[2], (__bf16)x1[3]};
        *(bf16x8*)&sV[d][j0] = vv;
    }

    // ---- Q split to hi+lo bf16 in registers ----
    bf16x8 qh, ql;
    #pragma unroll
    for (int e = 0; e < 8; ++e) {
        __bf16 hh = (__bf16)qv[e];
        qh[e] = hh;
        ql[e] = (__bf16)(qv[e] - (float)hh);
    }

    __syncthreads();

    // ---- S^T[j][i] = sum_d K^T[j][d] * Q[d][i] (split-bf16, 3 MFMAs/tile) ----
    const float ga = gammag[h], be = biasg[h];
    float s[16];
    #pragma unroll
    for (int jt = 0; jt < 4; ++jt) {
        const int j = jt * 16 + li;
        const int slot = hi ^ ((j >> 3) & 3);
        bf16x8 ah = *(bf16x8*)&sKh[j][slot * 8];
        bf16x8 al = *(bf16x8*)&sKl[j][slot * 8];
        f32x4 c = {0.f, 0.f, 0.f, 0.f};
        c = MFMA16(al, qh, c);   // lo*hi
        c = MFMA16(ah, ql, c);   // hi*lo
        c = MFMA16(ah, qh, c);   // hi*hi
        #pragma unroll
        for (int r = 0; r < 4; ++r) {
            float x = c[r] * ga + be;
            if ((mw[jt] >> (8 * r)) & 0xffu) x = -1.0e9f;
            s[jt * 4 + r] = x;
        }
    }

    // ---- softmax over j: 16 in-lane values + 2 shuffles (lanes share i) ----
    float m = s[0];
    #pragma unroll
    for (int e = 1; e < 16; ++e) m = fmaxf(m, s[e]);
    m = fmaxf(m, __shfl_xor(m, 16));
    m = fmaxf(m, __shfl_xor(m, 32));
    float p[16], sum = 0.f;
    #pragma unroll
    for (int e = 0; e < 16; ++e) { p[e] = __expf(s[e] - m); sum += p[e]; }
    sum += __shfl_xor(sum, 16);
    sum += __shfl_xor(sum, 32);
    const float inv = 1.0f / sum;

    // ---- gate: w = softmax * sigmoid; keep in registers as PV B-fragments ----
    bf16x4 wv[4];
    #pragma unroll
    for (int jt = 0; jt < 4; ++jt) {
        #pragma unroll
        for (int r = 0; r < 4; ++r) {
            const int e = jt * 4 + r;
            const float g = 1.0f / (1.0f + __expf(-s[e]));
            wv[jt][r] = (__bf16)(p[e] * inv * g);
        }
    }

    // ---- out[d][i] = sum_j V[d][j] * W[i][j], k-slots remapped so the
    //      in-register wv[] IS the B-fragment (no sW round-trip, no barrier) ----
    f32x4 o0 = {0.f, 0.f, 0.f, 0.f};
    f32x4 o1 = {0.f, 0.f, 0.f, 0.f};
    #pragma unroll
    for (int kt = 0; kt < 2; ++kt) {
        bf16x4 wlo = wv[2 * kt], whi = wv[2 * kt + 1];
        bf16x8 wb = {wlo[0], wlo[1], wlo[2], wlo[3], whi[0], whi[1], whi[2], whi[3]};
        const int c0 = kt * 32 + hi * 4;        // j-block for slots hi*8..+3
        const int c1 = kt * 32 + 16 + hi * 4;   // j-block for slots hi*8+4..+7
        bf16x4 a0l = *(const bf16x4*)&sV[li][c0];
        bf16x4 a0h = *(const bf16x4*)&sV[li][c1];
        bf16x8 va = {a0l[0], a0l[1], a0l[2], a0l[3], a0h[0], a0h[1], a0h[2], a0h[3]};
        bf16x4 a1l = *(const bf16x4*)&sV[16 + li][c0];
        bf16x4 a1h = *(const bf16x4*)&sV[16 + li][c1];
        bf16x8 vc = {a1l[0], a1l[1], a1l[2], a1l[3], a1h[0], a1h[1], a1h[2], a1h[3]};
        o0 = MFMA16(va, wb, o0);
        o1 = MFMA16(vc, wb, o1);
    }
    #pragma unroll
    for (int r = 0; r < 4; ++r) {
        ob[(hi * 4 + r) * 64 + i]      = o0[r];
        ob[(16 + hi * 4 + r) * 64 + i] = o1[r];
    }
}

extern "C" void kernel_launch(void* const* d_in, const int* in_sizes, int n_in,
                              void* d_out, int out_size, void* d_ws, size_t ws_size,
                              hipStream_t stream)
{
    const float* q = (const float*)d_in[0];
    const float* k = (const float*)d_in[1];
    const float* v = (const float*)d_in[2];
    const unsigned char* mask = (const unsigned char*)d_in[3];
    const float* gamma = (const float*)d_in[4];
    const float* bias  = (const float*)d_in[5];
    float* out = (float*)d_out;

    const int num_bh = in_sizes[0] / 2048;   // bs*h = 16384
    dim3 grid(num_bh), block(256);
    hipLaunchKernelGGL(mha_fused, grid, block, 0, stream,
                       q, k, v, mask, gamma, bias, out);
}